// Round 10
// baseline (390.363 us; speedup 1.0000x reference)
//
#include <hip/hip_runtime.h>

#define TSEQ   2048
#define CDIM   2048
#define NHEAD  16
#define DHEAD  128
#define NBATCH 2
#define MROWS  (NBATCH * TSEQ)   // 4096
#define WIN    512

typedef unsigned short u16;
typedef __attribute__((ext_vector_type(8))) short short8;   // 8 bf16 (4 VGPRs)
typedef __attribute__((ext_vector_type(4))) float f32x4;
typedef __attribute__((ext_vector_type(16))) float f32x16;
typedef __attribute__((ext_vector_type(4))) u16 u16x4;
typedef __attribute__((ext_vector_type(8))) u16 u16x8;

__device__ __forceinline__ void gload_lds16(const void* g, void* l) {
  __builtin_amdgcn_global_load_lds(
      (const __attribute__((address_space(1))) unsigned int*)g,
      (__attribute__((address_space(3))) unsigned int*)l, 16, 0, 0);
}

__device__ __forceinline__ u16 f2bf(float f) {
  unsigned u = __float_as_uint(f);
  u += 0x7fffu + ((u >> 16) & 1u);   // RNE
  return (u16)(u >> 16);
}
__device__ __forceinline__ float bf2f(u16 h) {
  return __uint_as_float((unsigned)h << 16);
}

// ---------------------------------------------------------------------------
// Weight transpose + fp32->bf16 (z<4): WT[n*C + k] = bf16(W[k*C + n]).
// z==4 plane: bulk convert x fp32 -> bf16 (2 float4 per thread).
// ---------------------------------------------------------------------------
__global__ __launch_bounds__(256) void transpose_kernel(
    const float* __restrict__ i0, const float* __restrict__ i1,
    const float* __restrict__ i2, const float* __restrict__ i3,
    u16* __restrict__ o0, u16* __restrict__ o1,
    u16* __restrict__ o2, u16* __restrict__ o3,
    const float* __restrict__ xin, u16* __restrict__ xout) {
  const int z = blockIdx.z;
  if (z == 4) {
    const int tf = threadIdx.y * 32 + threadIdx.x;
    const int base = (blockIdx.y * 64 + blockIdx.x) * 512 + tf * 2;
#pragma unroll
    for (int c = 0; c < 2; ++c) {
      const float4 v = ((const float4*)xin)[base + c];
      u16x4 ov;
      ov[0] = f2bf(v.x); ov[1] = f2bf(v.y); ov[2] = f2bf(v.z); ov[3] = f2bf(v.w);
      ((u16x4*)xout)[base + c] = ov;
    }
    return;
  }
  const float* in = (z == 0) ? i0 : (z == 1) ? i1 : (z == 2) ? i2 : i3;
  u16*       out = (z == 0) ? o0 : (z == 1) ? o1 : (z == 2) ? o2 : o3;
  __shared__ u16 tile[32][33];
  const int x  = blockIdx.x * 32 + threadIdx.x;
  const int y0 = blockIdx.y * 32 + threadIdx.y;
#pragma unroll
  for (int i = 0; i < 32; i += 8)
    tile[threadIdx.y + i][threadIdx.x] = f2bf(in[(size_t)(y0 + i) * CDIM + x]);
  __syncthreads();
  const int x2 = blockIdx.y * 32 + threadIdx.x;
  const int y2 = blockIdx.x * 32 + threadIdx.y;
#pragma unroll
  for (int i = 0; i < 32; i += 8)
    out[(size_t)(y2 + i) * CDIM + x2] = tile[threadIdx.x][threadIdx.y + i];
}

// ---------------------------------------------------------------------------
// RoPE tables: ct/st[t*64 + i] = cos/sin(t * 10000^(-i/64))
// ---------------------------------------------------------------------------
__global__ __launch_bounds__(256) void rope_table_kernel(float* __restrict__ ct,
                                                         float* __restrict__ st) {
  const int idx = blockIdx.x * 256 + threadIdx.x;   // < TSEQ*64
  const int t = idx >> 6, i = idx & 63;
  const float inv = exp2f(-(float)i * (13.287712379549449f / 64.0f)); // log2(10000)/64
  const float f = (float)t * inv;
  ct[idx] = cosf(f);
  st[idx] = sinf(f);
}

// ---------------------------------------------------------------------------
// BK=64 GEMM: C[M=4096, N=2048] = A[M,K=2048] * Bt[N,K]^T, bf16 internal.
// 128x128 tile, 4 waves, 16x16x32 MFMA, global_load_lds width 16.
// R10: XCD-aware block remap (xcd = flat%8 owns n-tile pair {2xcd,2xcd+1}
// x all m, m fastest -> 1MB B-slice L2-resident per XCD; was: 16 n-blocks
// of one (z,m) round-robined over 8 XCDs re-fetching 8MB B-panels,
// FETCH 109MB). Same formula serves both launches (gridDim.y in {1,3}).
// R10: RoPE fused into the q/k epilogue (ct != null, z != vz): rotate-half
// pair (d, d+64) exchanged through the As/Bs LDS (free after main loop) as
// bf16; u_self kept fp32. Deletes the rope_apply kernel (64MB traffic).
// Epilogues: OF!=null -> fp32 natural; z==vz -> bf16 vT; else bf16 (+rope).
// ---------------------------------------------------------------------------
__global__ __launch_bounds__(256, 4) void gemm_bt_kernel(
    const u16* __restrict__ A,
    const u16* __restrict__ B0, const u16* __restrict__ B1, const u16* __restrict__ B2,
    u16* __restrict__ O0, u16* __restrict__ O1, u16* __restrict__ O2,
    int vz, float* __restrict__ OF,
    const float* __restrict__ ct, const float* __restrict__ st) {
  __shared__ u16 sm[16384];        // As | Bs; epilogue reuses as rope exchange
  u16* As = sm;                    // [128][64] swizzled
  u16* Bs = sm + 8192;

  const int tid  = threadIdx.x;
  const int wave = tid >> 6;
  const int lane = tid & 63;
  const int quad = lane >> 4;
  const int l15  = lane & 15;

  // XCD-aware remap (bijective for gridDim (16, gy, 32), gy*2 z-planes... 
  // gy=3: z in {0,1,2}; gy=1: z=0).
  const int flat = blockIdx.x + 16 * (blockIdx.y + gridDim.y * blockIdx.z);
  const int xcd  = flat & 7;
  const int idx  = flat >> 3;
  const int rest = idx >> 5;
  const int z    = rest >> 1;
  const int bm   = (idx & 31) * 128;
  const int bn   = (xcd * 2 + (rest & 1)) * 128;

  const u16* Bt = (z == 0) ? B0 : (z == 1) ? B1 : B2;
  u16*       O  = (z == 0) ? O0 : (z == 1) ? O1 : O2;

  const int rlo = lane >> 3;                     // 0..7
  const int swb = ((lane & 7) + rlo) & 7;        // swizzled source block
  const u16* Ag = A  + (size_t)(bm + wave * 32 + rlo) * CDIM + swb * 8;
  const u16* Bg = Bt + (size_t)(bn + wave * 32 + rlo) * CDIM + swb * 8;
  u16* AsW = As + wave * 2048 + lane * 8;
  u16* BsW = Bs + wave * 2048 + lane * 8;

  const f32x4 zero4 = {0.f, 0.f, 0.f, 0.f};
  f32x4 acc[4][4];
#pragma unroll
  for (int mt = 0; mt < 4; ++mt)
#pragma unroll
    for (int nt = 0; nt < 4; ++nt) acc[mt][nt] = zero4;

  const int mh = (wave >> 1) * 64;
  const int nh = (wave & 1) * 64;

  const int off0 = ((quad - l15) & 7) * 8;       // ks = 0
  const int off1 = off0 ^ 32;                    // ks = 1

  for (int kb = 0; kb < CDIM; kb += 64) {
#pragma unroll
    for (int g = 0; g < 4; ++g) {
      gload_lds16(Ag + kb + (size_t)g * 8 * CDIM, AsW + g * 512);
      gload_lds16(Bg + kb + (size_t)g * 8 * CDIM, BsW + g * 512);
    }
    __syncthreads();

#pragma unroll
    for (int ks = 0; ks < 2; ++ks) {
      const int fo = ks ? off1 : off0;
      short8 af[4], bfr[4];
#pragma unroll
      for (int t = 0; t < 4; ++t) {
        af[t]  = *(const short8*)(As + (mh + t * 16 + l15) * 64 + fo);
        bfr[t] = *(const short8*)(Bs + (nh + t * 16 + l15) * 64 + fo);
      }
#pragma unroll
      for (int mt = 0; mt < 4; ++mt)
#pragma unroll
        for (int nt = 0; nt < 4; ++nt)
          acc[mt][nt] = __builtin_amdgcn_mfma_f32_16x16x32_bf16(af[mt], bfr[nt],
                                                                acc[mt][nt], 0, 0, 0);
    }
    __syncthreads();
  }

  if (OF != nullptr) {
#pragma unroll
    for (int mt = 0; mt < 4; ++mt) {
      const int row0 = bm + mh + mt * 16 + quad * 4;
#pragma unroll
      for (int nt = 0; nt < 4; ++nt) {
        const int col = bn + nh + nt * 16 + l15;
#pragma unroll
        for (int r = 0; r < 4; ++r)
          OF[(size_t)(row0 + r) * CDIM + col] = acc[mt][nt][r];
      }
    }
  } else if (z != vz) {
    if (ct != nullptr) {
      // RoPE-fused epilogue (q/k planes). Pair (wave, wave^1) shares rows
      // [mh, mh+64); exchange the (d, d+64) partner halves through LDS.
      u16* eps = sm + (wave >> 1) * 8192;   // [64 rows][128 cols] bf16
#pragma unroll
      for (int mt = 0; mt < 4; ++mt)
#pragma unroll
        for (int nt = 0; nt < 4; ++nt) {
          const int lcol = nh + nt * 16 + l15;
#pragma unroll
          for (int r = 0; r < 4; ++r)
            eps[(mt * 16 + quad * 4 + r) * 128 + lcol] = f2bf(acc[mt][nt][r]);
        }
      __syncthreads();
#pragma unroll
      for (int mt = 0; mt < 4; ++mt)
#pragma unroll
        for (int r = 0; r < 4; ++r) {
          const int lrow = mt * 16 + quad * 4 + r;
          const int grow = bm + mh + lrow;
          const int t = grow & (TSEQ - 1);
#pragma unroll
          for (int nt = 0; nt < 4; ++nt) {
            const int lcol = nh + nt * 16 + l15;
            const int i = lcol & 63;
            const float c = ct[t * 64 + i];
            const float s = st[t * 64 + i];
            const float us = acc[mt][nt][r];
            const float uo = bf2f(eps[lrow * 128 + (lcol ^ 64)]);
            // d<64: y = u1*c - u2*s ; d>=64: y = u1*s + u2*c
            const float val = (nh == 0) ? (us * c - uo * s) : (uo * s + us * c);
            O[(size_t)grow * CDIM + (bn + lcol)] = f2bf(val);
          }
        }
    } else {
#pragma unroll
      for (int mt = 0; mt < 4; ++mt) {
        const int row0 = bm + mh + mt * 16 + quad * 4;
#pragma unroll
        for (int nt = 0; nt < 4; ++nt) {
          const int col = bn + nh + nt * 16 + l15;
#pragma unroll
          for (int r = 0; r < 4; ++r)
            O[(size_t)(row0 + r) * CDIM + col] = f2bf(acc[mt][nt][r]);
        }
      }
    }
  } else {
    // v epilogue: O = vT[(b*H + head)*D + d][t]; packed 8B store
    const int head = bn >> 7;
#pragma unroll
    for (int mt = 0; mt < 4; ++mt) {
      const int gm0 = bm + mh + mt * 16 + quad * 4;
      const int b  = gm0 >> 11;
      const int t0 = gm0 & (TSEQ - 1);
#pragma unroll
      for (int nt = 0; nt < 4; ++nt) {
        const int d = nh + nt * 16 + l15;
        u16x4 pk;
#pragma unroll
        for (int r = 0; r < 4; ++r) pk[r] = f2bf(acc[mt][nt][r]);
        *(u16x4*)(O + ((size_t)((b * NHEAD + head) * DHEAD + d)) * TSEQ + t0) = pk;
      }
    }
  }
}

// ---------------------------------------------------------------------------
// Flash attention — unchanged from R9 (new best): KVBLK=64, 4 independent
// QK^T chains, in-register softmax, gload_lds staging w/ pre-swizzled
// global source, XCD remap, 2 blocks/CU, 256 regs/wave (no spill).
// ---------------------------------------------------------------------------
__global__ __launch_bounds__(256, 2) void attn_kernel(
    const u16* __restrict__ q, const u16* __restrict__ k,
    const u16* __restrict__ vT, u16* __restrict__ o) {
  __shared__ u16 ks[2 * 64 * 128];   // [buf][key 64][chan 128], chunk-swizzled
  __shared__ u16 vs[2 * 128 * 64];   // [buf][d 128][key 64], chunk-swizzled

  const int tid  = threadIdx.x;        // 0..255
  const int wave = tid >> 6;           // 0..3 = q-subtile
  const int lane = tid & 63;
  const int hi   = lane >> 5;          // k-half select in 32x32x16 fragments
  const int l31  = lane & 31;

  const int flat = blockIdx.y * 16 + blockIdx.x;   // [0,512)
  const int qb   = (flat >> 3) & 15;
  const int bh   = (flat & 7) * 4 + (flat >> 7);   // b*16 + h
  const int b    = bh >> 4;
  const int h    = bh & 15;
  const int qw0  = qb * 128 + wave * 32;
  const int qi   = qw0 + l31;          // this lane's q row (col of S^T)

  // Q B-fragments: qf[s] = Q[qi][s*16 + hi*8 .. +8]
  short8 qf[8];
  {
    const u16* qrow = q + ((size_t)(b * TSEQ + qi)) * CDIM + h * DHEAD + hi * 8;
#pragma unroll
    for (int s = 0; s < 8; ++s) qf[s] = *(const short8*)(qrow + s * 16);
  }

  f32x16 oacc[4];   // [dt]: O^T[d = dt*32 + (r&3)+8*(r>>2)+4*hi][q = qi]
#pragma unroll
  for (int dt = 0; dt < 4; ++dt)
#pragma unroll
    for (int r = 0; r < 16; ++r) oacc[dt][r] = 0.f;
  float lrow = 0.f;

  const u16* kbase = k + ((size_t)(b * TSEQ)) * CDIM + h * DHEAD;
  const u16* vbase = vT + ((size_t)bh) * DHEAD * TSEQ;
  const float SC  = 0.08838834764831845f * 1.4426950408889634f; // 1/sqrt(128)*log2e
  const float MSH = 12.0f;   // fixed softmax shift (log2 domain)

  // remap out fully-block-masked 64-key tiles: t in [2qb-6, 2qb-1]
  int tlo = 2 * qb - 6; if (tlo < 0) tlo = 0;
  int nskip = (2 * qb - 1) - tlo + 1; if (nskip < 0) nskip = 0;
  const int nact = 32 - nskip;   // 26..32
  auto jof = [&](int a) { return ((a < tlo) ? a : a + nskip) * 64; };

  // gload_lds staging: per wave 4 K + 4 V gloads per 64-key tile.
  const int krA = wave * 16 + (lane >> 4);             // g=0 row
  const int krB = krA + 4;                             // g=1 row
  const int kc  = lane & 15;
  const u16* kgpA = kbase + (size_t)krA * CDIM + ((kc ^ (krA & 7)) * 8);
  const u16* kgpB = kbase + (size_t)krB * CDIM + ((kc ^ (krB & 7)) * 8);
  const int vr  = wave * 32 + (lane >> 3);
  const int vc  = lane & 7;
  const u16* vgp = vbase + (size_t)vr * TSEQ + ((vc ^ (vr & 7)) * 8);
  u16* ksw = ks + (wave * 16) * 128 + lane * 8;        // buf0; buf1 = +8192
  u16* vsw = vs + (wave * 32) * 64 + lane * 8;

  auto stage = [&](int j, int buf) {
    const int off = buf * 8192;
#pragma unroll
    for (int g = 0; g < 4; ++g) {
      const u16* kg = (g & 1) ? kgpB : kgpA;
      gload_lds16(kg + (size_t)(j + (g >> 1) * 8) * CDIM, ksw + off + g * 512);
      gload_lds16(vgp + j + (size_t)(g * 8) * TSEQ, vsw + off + g * 512);
    }
  };

  stage(jof(0), 0);
  __syncthreads();

  for (int it = 0; it < nact; ++it) {
    const int p = it & 1;
    const int j0 = jof(it);

    if (it + 1 < nact) stage(jof(it + 1), 1 - p);

    const u16* ksp = ks + p * 8192;
    const u16* vsp = vs + p * 8192;

    const bool wskip = (j0 + 63 <= qw0) && (j0 >= qw0 + 31 - (WIN - 1));
    if (!wskip) {
      // S^T = K * Q^T: two 32x32 key-subtiles, 4 independent MFMA chains.
      f32x16 sa0, sb0, sa1, sb1;
#pragma unroll
      for (int r = 0; r < 16; ++r) { sa0[r] = 0.f; sb0[r] = 0.f; sa1[r] = 0.f; sb1[r] = 0.f; }
#pragma unroll
      for (int s = 0; s < 8; s += 2) {
        const int c0 = ((s * 2 + hi) ^ (l31 & 7)) * 8;
        const int c1 = (((s + 1) * 2 + hi) ^ (l31 & 7)) * 8;
        const short8 k00 = *(const short8*)(ksp + l31 * 128 + c0);
        const short8 k01 = *(const short8*)(ksp + l31 * 128 + c1);
        const short8 k10 = *(const short8*)(ksp + (32 + l31) * 128 + c0);
        const short8 k11 = *(const short8*)(ksp + (32 + l31) * 128 + c1);
        sa0 = __builtin_amdgcn_mfma_f32_32x32x16_bf16(k00, qf[s],     sa0, 0, 0, 0);
        sb0 = __builtin_amdgcn_mfma_f32_32x32x16_bf16(k01, qf[s + 1], sb0, 0, 0, 0);
        sa1 = __builtin_amdgcn_mfma_f32_32x32x16_bf16(k10, qf[s],     sa1, 0, 0, 0);
        sb1 = __builtin_amdgcn_mfma_f32_32x32x16_bf16(k11, qf[s + 1], sb1, 0, 0, 0);
      }
      const f32x16 sf0 = sa0 + sb0;
      const f32x16 sf1 = sa1 + sb1;

      float pe0[16], pe1[16];
      const bool hasMask = (qw0 + 31 >= j0) && (qw0 <= j0 + 63 + (WIN - 1));
      if (hasMask) {
#pragma unroll
        for (int r = 0; r < 16; ++r) {
          const int ko = (r & 3) + 8 * (r >> 2) + 4 * hi;
          const int kj0 = j0 + ko, kj1 = j0 + 32 + ko;
          const float e0 = exp2f(fmaf(sf0[r], SC, -MSH));
          const float e1 = exp2f(fmaf(sf1[r], SC, -MSH));
          pe0[r] = ((unsigned)(qi - kj0) < (unsigned)WIN) ? 0.f : e0;
          pe1[r] = ((unsigned)(qi - kj1) < (unsigned)WIN) ? 0.f : e1;
        }
      } else {
#pragma unroll
        for (int r = 0; r < 16; ++r) {
          pe0[r] = exp2f(fmaf(sf0[r], SC, -MSH));
          pe1[r] = exp2f(fmaf(sf1[r], SC, -MSH));
        }
      }
#pragma unroll
      for (int r = 0; r < 16; ++r) lrow += pe0[r] + pe1[r];

      short8 pf[2][2];   // [jt][kk]: B[k = jt*32+kk*16 .. +16][q]
#pragma unroll
      for (int jt = 0; jt < 2; ++jt) {
        const float* pe = jt ? pe1 : pe0;
        int D0, D1, D2, D3, D4, D5, D6, D7;
        asm("v_cvt_pk_bf16_f32 %0, %1, %2" : "=v"(D0) : "v"(pe[0]),  "v"(pe[1]));
        asm("v_cvt_pk_bf16_f32 %0, %1, %2" : "=v"(D1) : "v"(pe[2]),  "v"(pe[3]));
        asm("v_cvt_pk_bf16_f32 %0, %1, %2" : "=v"(D2) : "v"(pe[4]),  "v"(pe[5]));
        asm("v_cvt_pk_bf16_f32 %0, %1, %2" : "=v"(D3) : "v"(pe[6]),  "v"(pe[7]));
        asm("v_cvt_pk_bf16_f32 %0, %1, %2" : "=v"(D4) : "v"(pe[8]),  "v"(pe[9]));
        asm("v_cvt_pk_bf16_f32 %0, %1, %2" : "=v"(D5) : "v"(pe[10]), "v"(pe[11]));
        asm("v_cvt_pk_bf16_f32 %0, %1, %2" : "=v"(D6) : "v"(pe[12]), "v"(pe[13]));
        asm("v_cvt_pk_bf16_f32 %0, %1, %2" : "=v"(D7) : "v"(pe[14]), "v"(pe[15]));
        asm("v_permlane32_swap_b32 %0, %1" : "+v"(D0), "+v"(D2));
        asm("v_permlane32_swap_b32 %0, %1" : "+v"(D1), "+v"(D3));
        asm("v_permlane32_swap_b32 %0, %1" : "+v"(D4), "+v"(D6));
        asm("v_permlane32_swap_b32 %0, %1" : "+v"(D5), "+v"(D7));
        union { int i[4]; short8 s8; } u0, u1;
        u0.i[0] = D0; u0.i[1] = D1; u0.i[2] = D2; u0.i[3] = D3;
        u1.i[0] = D4; u1.i[1] = D5; u1.i[2] = D6; u1.i[3] = D7;
        pf[jt][0] = u0.s8;
        pf[jt][1] = u1.s8;
      }

#pragma unroll
      for (int dt = 0; dt < 4; ++dt) {
        const u16* vrow = vsp + (dt * 32 + l31) * 64;
        const int sw = (l31 & 7);
#pragma unroll
        for (int jt = 0; jt < 2; ++jt) {
          const short8 vf0 = *(const short8*)(vrow + (((jt * 4 + 0) + hi) ^ sw) * 8);
          const short8 vf1 = *(const short8*)(vrow + (((jt * 4 + 2) + hi) ^ sw) * 8);
          oacc[dt] = __builtin_amdgcn_mfma_f32_32x32x16_bf16(vf0, pf[jt][0], oacc[dt], 0, 0, 0);
          oacc[dt] = __builtin_amdgcn_mfma_f32_32x32x16_bf16(vf1, pf[jt][1], oacc[dt], 0, 0, 0);
        }
      }
    }

    __syncthreads();   // drains vmcnt (prefetch landed) + frees buf p
  }

  lrow += __shfl_xor(lrow, 32, 64);
  const float inv = 1.0f / lrow;

  u16* obase = o + ((size_t)(b * TSEQ + qi)) * CDIM + h * DHEAD;
#pragma unroll
  for (int dt = 0; dt < 4; ++dt)
#pragma unroll
    for (int a2 = 0; a2 < 4; ++a2) {
      u16x4 pkd;
#pragma unroll
      for (int r = 0; r < 4; ++r) pkd[r] = f2bf(oacc[dt][a2 * 4 + r] * inv);
      *(u16x4*)(obase + dt * 32 + a2 * 8 + hi * 4) = pkd;
    }
}

// ---------------------------------------------------------------------------
extern "C" void kernel_launch(void* const* d_in, const int* in_sizes, int n_in,
                              void* d_out, int out_size, void* d_ws, size_t ws_size,
                              hipStream_t stream) {
  (void)in_sizes; (void)n_in; (void)out_size; (void)ws_size;
  const float* x  = (const float*)d_in[0];
  const float* Wq = (const float*)d_in[1];
  const float* Wk = (const float*)d_in[2];
  const float* Wv = (const float*)d_in[3];
  const float* Wo = (const float*)d_in[4];
  float* out = (float*)d_out;

  char* ws = (char*)d_ws;
  const size_t WT = (size_t)CDIM * CDIM * sizeof(u16);   // 8 MiB
  const size_t QS = (size_t)MROWS * CDIM * sizeof(u16);  // 16 MiB
  u16* WqT = (u16*)(ws + 0 * WT);
  u16* WkT = (u16*)(ws + 1 * WT);
  u16* WvT = (u16*)(ws + 2 * WT);
  u16* WoT = (u16*)(ws + 3 * WT);
  u16* xb  = (u16*)(ws + 4 * WT);
  u16* qb  = (u16*)(ws + 4 * WT + 1 * QS);
  u16* kb  = (u16*)(ws + 4 * WT + 2 * QS);
  u16* vTb = (u16*)(ws + 4 * WT + 3 * QS);
  u16* ob  = (u16*)(ws + 4 * WT + 4 * QS);
  float* ct = (float*)(ws + 4 * WT + 5 * QS);
  float* st = ct + TSEQ * 64;

  transpose_kernel<<<dim3(64, 64, 5), dim3(32, 8), 0, stream>>>(
      Wq, Wk, Wv, Wo, WqT, WkT, WvT, WoT, x, xb);
  rope_table_kernel<<<dim3(TSEQ * 64 / 256), 256, 0, stream>>>(ct, st);
  gemm_bt_kernel<<<dim3(16, 3, 32), 256, 0, stream>>>(
      xb, WqT, WkT, WvT, qb, kb, vTb, 2, nullptr, ct, st);
  attn_kernel<<<dim3(16, 32), 256, 0, stream>>>(qb, kb, vTb, ob);
  gemm_bt_kernel<<<dim3(16, 1, 32), 256, 0, stream>>>(
      ob, WoT, WoT, WoT, nullptr, nullptr, nullptr, -1, out, nullptr, nullptr);
}

// Round 11
// 372.582 us; speedup vs baseline: 1.0477x; 1.0477x over previous
//
#include <hip/hip_runtime.h>

#define TSEQ   2048
#define CDIM   2048
#define NHEAD  16
#define DHEAD  128
#define NBATCH 2
#define MROWS  (NBATCH * TSEQ)   // 4096
#define WIN    512

typedef unsigned short u16;
typedef __attribute__((ext_vector_type(8))) short short8;   // 8 bf16 (4 VGPRs)
typedef __attribute__((ext_vector_type(4))) float f32x4;
typedef __attribute__((ext_vector_type(16))) float f32x16;
typedef __attribute__((ext_vector_type(4))) u16 u16x4;
typedef __attribute__((ext_vector_type(8))) u16 u16x8;

__device__ __forceinline__ void gload_lds16(const void* g, void* l) {
  __builtin_amdgcn_global_load_lds(
      (const __attribute__((address_space(1))) unsigned int*)g,
      (__attribute__((address_space(3))) unsigned int*)l, 16, 0, 0);
}

__device__ __forceinline__ u16 f2bf(float f) {
  unsigned u = __float_as_uint(f);
  u += 0x7fffu + ((u >> 16) & 1u);   // RNE
  return (u16)(u >> 16);
}
__device__ __forceinline__ float bf2f(u16 h) {
  return __uint_as_float((unsigned)h << 16);
}

// ---------------------------------------------------------------------------
// Weight transpose + fp32->bf16 (z<4): WT[n*C + k] = bf16(W[k*C + n]).
// z==4 plane: bulk convert x fp32 -> bf16 (2 float4 per thread).
// ---------------------------------------------------------------------------
__global__ __launch_bounds__(256) void transpose_kernel(
    const float* __restrict__ i0, const float* __restrict__ i1,
    const float* __restrict__ i2, const float* __restrict__ i3,
    u16* __restrict__ o0, u16* __restrict__ o1,
    u16* __restrict__ o2, u16* __restrict__ o3,
    const float* __restrict__ xin, u16* __restrict__ xout) {
  const int z = blockIdx.z;
  if (z == 4) {
    const int tf = threadIdx.y * 32 + threadIdx.x;
    const int base = (blockIdx.y * 64 + blockIdx.x) * 512 + tf * 2;
#pragma unroll
    for (int c = 0; c < 2; ++c) {
      const float4 v = ((const float4*)xin)[base + c];
      u16x4 ov;
      ov[0] = f2bf(v.x); ov[1] = f2bf(v.y); ov[2] = f2bf(v.z); ov[3] = f2bf(v.w);
      ((u16x4*)xout)[base + c] = ov;
    }
    return;
  }
  const float* in = (z == 0) ? i0 : (z == 1) ? i1 : (z == 2) ? i2 : i3;
  u16*       out = (z == 0) ? o0 : (z == 1) ? o1 : (z == 2) ? o2 : o3;
  __shared__ u16 tile[32][33];
  const int x  = blockIdx.x * 32 + threadIdx.x;
  const int y0 = blockIdx.y * 32 + threadIdx.y;
#pragma unroll
  for (int i = 0; i < 32; i += 8)
    tile[threadIdx.y + i][threadIdx.x] = f2bf(in[(size_t)(y0 + i) * CDIM + x]);
  __syncthreads();
  const int x2 = blockIdx.y * 32 + threadIdx.x;
  const int y2 = blockIdx.x * 32 + threadIdx.y;
#pragma unroll
  for (int i = 0; i < 32; i += 8)
    out[(size_t)(y2 + i) * CDIM + x2] = tile[threadIdx.x][threadIdx.y + i];
}

// ---------------------------------------------------------------------------
// RoPE tables: ct/st[t*64 + i] = cos/sin(t * 10000^(-i/64))
// ---------------------------------------------------------------------------
__global__ __launch_bounds__(256) void rope_table_kernel(float* __restrict__ ct,
                                                         float* __restrict__ st) {
  const int idx = blockIdx.x * 256 + threadIdx.x;   // < TSEQ*64
  const int t = idx >> 6, i = idx & 63;
  const float inv = exp2f(-(float)i * (13.287712379549449f / 64.0f)); // log2(10000)/64
  const float f = (float)t * inv;
  ct[idx] = cosf(f);
  st[idx] = sinf(f);
}

// ---------------------------------------------------------------------------
// BK=64 GEMM: C[M=4096, N=2048] = A[M,K=2048] * Bt[N,K]^T, bf16 internal.
// 128x128 tile, 4 waves, 16x16x32 MFMA, global_load_lds width 16.
// R11: default block mapping restored (R10's XCD remap REGRESSED: default
// order already pins each XCD to n-cols {x, x+8} with temporally-coherent
// A sweep; the remap made each XCD re-stream the 16MB A 6x -> FETCH
// 109->296MB, dur 101->115us).
// Kept from R10: RoPE fused into the q/k epilogue (ct != null, z != vz):
// rotate-half pair (d, d+64) exchanged through LDS (free after main loop),
// bf16, stride padded to 136 u16 (272B rows -> quads on distinct bank
// groups, kills the 1e6 conflict cycles). Deletes rope_apply (64MB).
// Epilogues: OF!=null -> fp32 natural; z==vz -> bf16 vT; else bf16 (+rope).
// ---------------------------------------------------------------------------
__global__ __launch_bounds__(256, 4) void gemm_bt_kernel(
    const u16* __restrict__ A,
    const u16* __restrict__ B0, const u16* __restrict__ B1, const u16* __restrict__ B2,
    u16* __restrict__ O0, u16* __restrict__ O1, u16* __restrict__ O2,
    int vz, float* __restrict__ OF,
    const float* __restrict__ ct, const float* __restrict__ st) {
  __shared__ u16 sm[2 * 64 * 136];  // main loop: As|Bs (16384 u16); epilogue:
  u16* As = sm;                     // two 64x136 rope-exchange regions
  u16* Bs = sm + 8192;

  const int tid  = threadIdx.x;
  const int wave = tid >> 6;
  const int lane = tid & 63;
  const int quad = lane >> 4;
  const int l15  = lane & 15;

  const int z  = blockIdx.y;
  const int bm = blockIdx.z * 128;
  const int bn = blockIdx.x * 128;

  const u16* Bt = (z == 0) ? B0 : (z == 1) ? B1 : B2;
  u16*       O  = (z == 0) ? O0 : (z == 1) ? O1 : O2;

  const int rlo = lane >> 3;                     // 0..7
  const int swb = ((lane & 7) + rlo) & 7;        // swizzled source block
  const u16* Ag = A  + (size_t)(bm + wave * 32 + rlo) * CDIM + swb * 8;
  const u16* Bg = Bt + (size_t)(bn + wave * 32 + rlo) * CDIM + swb * 8;
  u16* AsW = As + wave * 2048 + lane * 8;
  u16* BsW = Bs + wave * 2048 + lane * 8;

  const f32x4 zero4 = {0.f, 0.f, 0.f, 0.f};
  f32x4 acc[4][4];
#pragma unroll
  for (int mt = 0; mt < 4; ++mt)
#pragma unroll
    for (int nt = 0; nt < 4; ++nt) acc[mt][nt] = zero4;

  const int mh = (wave >> 1) * 64;
  const int nh = (wave & 1) * 64;

  const int off0 = ((quad - l15) & 7) * 8;       // ks = 0
  const int off1 = off0 ^ 32;                    // ks = 1

  for (int kb = 0; kb < CDIM; kb += 64) {
#pragma unroll
    for (int g = 0; g < 4; ++g) {
      gload_lds16(Ag + kb + (size_t)g * 8 * CDIM, AsW + g * 512);
      gload_lds16(Bg + kb + (size_t)g * 8 * CDIM, BsW + g * 512);
    }
    __syncthreads();

#pragma unroll
    for (int ks = 0; ks < 2; ++ks) {
      const int fo = ks ? off1 : off0;
      short8 af[4], bfr[4];
#pragma unroll
      for (int t = 0; t < 4; ++t) {
        af[t]  = *(const short8*)(As + (mh + t * 16 + l15) * 64 + fo);
        bfr[t] = *(const short8*)(Bs + (nh + t * 16 + l15) * 64 + fo);
      }
#pragma unroll
      for (int mt = 0; mt < 4; ++mt)
#pragma unroll
        for (int nt = 0; nt < 4; ++nt)
          acc[mt][nt] = __builtin_amdgcn_mfma_f32_16x16x32_bf16(af[mt], bfr[nt],
                                                                acc[mt][nt], 0, 0, 0);
    }
    __syncthreads();
  }

  if (OF != nullptr) {
#pragma unroll
    for (int mt = 0; mt < 4; ++mt) {
      const int row0 = bm + mh + mt * 16 + quad * 4;
#pragma unroll
      for (int nt = 0; nt < 4; ++nt) {
        const int col = bn + nh + nt * 16 + l15;
#pragma unroll
        for (int r = 0; r < 4; ++r)
          OF[(size_t)(row0 + r) * CDIM + col] = acc[mt][nt][r];
      }
    }
  } else if (z != vz) {
    if (ct != nullptr) {
      // RoPE-fused epilogue (q/k planes). Pair (wave, wave^1) shares rows
      // [mh, mh+64); exchange the (d, d+64) partner halves through LDS.
      u16* eps = sm + (wave >> 1) * 8704;   // [64 rows][136 cols] bf16
#pragma unroll
      for (int mt = 0; mt < 4; ++mt)
#pragma unroll
        for (int nt = 0; nt < 4; ++nt) {
          const int lcol = nh + nt * 16 + l15;
#pragma unroll
          for (int r = 0; r < 4; ++r)
            eps[(mt * 16 + quad * 4 + r) * 136 + lcol] = f2bf(acc[mt][nt][r]);
        }
      __syncthreads();
#pragma unroll
      for (int mt = 0; mt < 4; ++mt)
#pragma unroll
        for (int r = 0; r < 4; ++r) {
          const int lrow = mt * 16 + quad * 4 + r;
          const int grow = bm + mh + lrow;
          const int t = grow & (TSEQ - 1);
#pragma unroll
          for (int nt = 0; nt < 4; ++nt) {
            const int lcol = nh + nt * 16 + l15;
            const int i = lcol & 63;
            const float c = ct[t * 64 + i];
            const float s = st[t * 64 + i];
            const float us = acc[mt][nt][r];
            const float uo = bf2f(eps[lrow * 136 + (lcol ^ 64)]);
            // d<64: y = u1*c - u2*s ; d>=64: y = u1*s + u2*c
            const float val = (nh == 0) ? (us * c - uo * s) : (uo * s + us * c);
            O[(size_t)grow * CDIM + (bn + lcol)] = f2bf(val);
          }
        }
    } else {
#pragma unroll
      for (int mt = 0; mt < 4; ++mt) {
        const int row0 = bm + mh + mt * 16 + quad * 4;
#pragma unroll
        for (int nt = 0; nt < 4; ++nt) {
          const int col = bn + nh + nt * 16 + l15;
#pragma unroll
          for (int r = 0; r < 4; ++r)
            O[(size_t)(row0 + r) * CDIM + col] = f2bf(acc[mt][nt][r]);
        }
      }
    }
  } else {
    // v epilogue: O = vT[(b*H + head)*D + d][t]; packed 8B store
    const int head = bn >> 7;
#pragma unroll
    for (int mt = 0; mt < 4; ++mt) {
      const int gm0 = bm + mh + mt * 16 + quad * 4;
      const int b  = gm0 >> 11;
      const int t0 = gm0 & (TSEQ - 1);
#pragma unroll
      for (int nt = 0; nt < 4; ++nt) {
        const int d = nh + nt * 16 + l15;
        u16x4 pk;
#pragma unroll
        for (int r = 0; r < 4; ++r) pk[r] = f2bf(acc[mt][nt][r]);
        *(u16x4*)(O + ((size_t)((b * NHEAD + head) * DHEAD + d)) * TSEQ + t0) = pk;
      }
    }
  }
}

// ---------------------------------------------------------------------------
// Flash attention — unchanged from R9 (best): KVBLK=64, 4 independent
// QK^T chains, in-register softmax, gload_lds staging w/ pre-swizzled
// global source, XCD remap, 2 blocks/CU, 256 regs/wave (no spill).
// ---------------------------------------------------------------------------
__global__ __launch_bounds__(256, 2) void attn_kernel(
    const u16* __restrict__ q, const u16* __restrict__ k,
    const u16* __restrict__ vT, u16* __restrict__ o) {
  __shared__ u16 ks[2 * 64 * 128];   // [buf][key 64][chan 128], chunk-swizzled
  __shared__ u16 vs[2 * 128 * 64];   // [buf][d 128][key 64], chunk-swizzled

  const int tid  = threadIdx.x;        // 0..255
  const int wave = tid >> 6;           // 0..3 = q-subtile
  const int lane = tid & 63;
  const int hi   = lane >> 5;          // k-half select in 32x32x16 fragments
  const int l31  = lane & 31;

  const int flat = blockIdx.y * 16 + blockIdx.x;   // [0,512)
  const int qb   = (flat >> 3) & 15;
  const int bh   = (flat & 7) * 4 + (flat >> 7);   // b*16 + h
  const int b    = bh >> 4;
  const int h    = bh & 15;
  const int qw0  = qb * 128 + wave * 32;
  const int qi   = qw0 + l31;          // this lane's q row (col of S^T)

  // Q B-fragments: qf[s] = Q[qi][s*16 + hi*8 .. +8]
  short8 qf[8];
  {
    const u16* qrow = q + ((size_t)(b * TSEQ + qi)) * CDIM + h * DHEAD + hi * 8;
#pragma unroll
    for (int s = 0; s < 8; ++s) qf[s] = *(const short8*)(qrow + s * 16);
  }

  f32x16 oacc[4];   // [dt]: O^T[d = dt*32 + (r&3)+8*(r>>2)+4*hi][q = qi]
#pragma unroll
  for (int dt = 0; dt < 4; ++dt)
#pragma unroll
    for (int r = 0; r < 16; ++r) oacc[dt][r] = 0.f;
  float lrow = 0.f;

  const u16* kbase = k + ((size_t)(b * TSEQ)) * CDIM + h * DHEAD;
  const u16* vbase = vT + ((size_t)bh) * DHEAD * TSEQ;
  const float SC  = 0.08838834764831845f * 1.4426950408889634f; // 1/sqrt(128)*log2e
  const float MSH = 12.0f;   // fixed softmax shift (log2 domain)

  // remap out fully-block-masked 64-key tiles: t in [2qb-6, 2qb-1]
  int tlo = 2 * qb - 6; if (tlo < 0) tlo = 0;
  int nskip = (2 * qb - 1) - tlo + 1; if (nskip < 0) nskip = 0;
  const int nact = 32 - nskip;   // 26..32
  auto jof = [&](int a) { return ((a < tlo) ? a : a + nskip) * 64; };

  // gload_lds staging: per wave 4 K + 4 V gloads per 64-key tile.
  const int krA = wave * 16 + (lane >> 4);             // g=0 row
  const int krB = krA + 4;                             // g=1 row
  const int kc  = lane & 15;
  const u16* kgpA = kbase + (size_t)krA * CDIM + ((kc ^ (krA & 7)) * 8);
  const u16* kgpB = kbase + (size_t)krB * CDIM + ((kc ^ (krB & 7)) * 8);
  const int vr  = wave * 32 + (lane >> 3);
  const int vc  = lane & 7;
  const u16* vgp = vbase + (size_t)vr * TSEQ + ((vc ^ (vr & 7)) * 8);
  u16* ksw = ks + (wave * 16) * 128 + lane * 8;        // buf0; buf1 = +8192
  u16* vsw = vs + (wave * 32) * 64 + lane * 8;

  auto stage = [&](int j, int buf) {
    const int off = buf * 8192;
#pragma unroll
    for (int g = 0; g < 4; ++g) {
      const u16* kg = (g & 1) ? kgpB : kgpA;
      gload_lds16(kg + (size_t)(j + (g >> 1) * 8) * CDIM, ksw + off + g * 512);
      gload_lds16(vgp + j + (size_t)(g * 8) * TSEQ, vsw + off + g * 512);
    }
  };

  stage(jof(0), 0);
  __syncthreads();

  for (int it = 0; it < nact; ++it) {
    const int p = it & 1;
    const int j0 = jof(it);

    if (it + 1 < nact) stage(jof(it + 1), 1 - p);

    const u16* ksp = ks + p * 8192;
    const u16* vsp = vs + p * 8192;

    const bool wskip = (j0 + 63 <= qw0) && (j0 >= qw0 + 31 - (WIN - 1));
    if (!wskip) {
      // S^T = K * Q^T: two 32x32 key-subtiles, 4 independent MFMA chains.
      f32x16 sa0, sb0, sa1, sb1;
#pragma unroll
      for (int r = 0; r < 16; ++r) { sa0[r] = 0.f; sb0[r] = 0.f; sa1[r] = 0.f; sb1[r] = 0.f; }
#pragma unroll
      for (int s = 0; s < 8; s += 2) {
        const int c0 = ((s * 2 + hi) ^ (l31 & 7)) * 8;
        const int c1 = (((s + 1) * 2 + hi) ^ (l31 & 7)) * 8;
        const short8 k00 = *(const short8*)(ksp + l31 * 128 + c0);
        const short8 k01 = *(const short8*)(ksp + l31 * 128 + c1);
        const short8 k10 = *(const short8*)(ksp + (32 + l31) * 128 + c0);
        const short8 k11 = *(const short8*)(ksp + (32 + l31) * 128 + c1);
        sa0 = __builtin_amdgcn_mfma_f32_32x32x16_bf16(k00, qf[s],     sa0, 0, 0, 0);
        sb0 = __builtin_amdgcn_mfma_f32_32x32x16_bf16(k01, qf[s + 1], sb0, 0, 0, 0);
        sa1 = __builtin_amdgcn_mfma_f32_32x32x16_bf16(k10, qf[s],     sa1, 0, 0, 0);
        sb1 = __builtin_amdgcn_mfma_f32_32x32x16_bf16(k11, qf[s + 1], sb1, 0, 0, 0);
      }
      const f32x16 sf0 = sa0 + sb0;
      const f32x16 sf1 = sa1 + sb1;

      float pe0[16], pe1[16];
      const bool hasMask = (qw0 + 31 >= j0) && (qw0 <= j0 + 63 + (WIN - 1));
      if (hasMask) {
#pragma unroll
        for (int r = 0; r < 16; ++r) {
          const int ko = (r & 3) + 8 * (r >> 2) + 4 * hi;
          const int kj0 = j0 + ko, kj1 = j0 + 32 + ko;
          const float e0 = exp2f(fmaf(sf0[r], SC, -MSH));
          const float e1 = exp2f(fmaf(sf1[r], SC, -MSH));
          pe0[r] = ((unsigned)(qi - kj0) < (unsigned)WIN) ? 0.f : e0;
          pe1[r] = ((unsigned)(qi - kj1) < (unsigned)WIN) ? 0.f : e1;
        }
      } else {
#pragma unroll
        for (int r = 0; r < 16; ++r) {
          pe0[r] = exp2f(fmaf(sf0[r], SC, -MSH));
          pe1[r] = exp2f(fmaf(sf1[r], SC, -MSH));
        }
      }
#pragma unroll
      for (int r = 0; r < 16; ++r) lrow += pe0[r] + pe1[r];

      short8 pf[2][2];   // [jt][kk]: B[k = jt*32+kk*16 .. +16][q]
#pragma unroll
      for (int jt = 0; jt < 2; ++jt) {
        const float* pe = jt ? pe1 : pe0;
        int D0, D1, D2, D3, D4, D5, D6, D7;
        asm("v_cvt_pk_bf16_f32 %0, %1, %2" : "=v"(D0) : "v"(pe[0]),  "v"(pe[1]));
        asm("v_cvt_pk_bf16_f32 %0, %1, %2" : "=v"(D1) : "v"(pe[2]),  "v"(pe[3]));
        asm("v_cvt_pk_bf16_f32 %0, %1, %2" : "=v"(D2) : "v"(pe[4]),  "v"(pe[5]));
        asm("v_cvt_pk_bf16_f32 %0, %1, %2" : "=v"(D3) : "v"(pe[6]),  "v"(pe[7]));
        asm("v_cvt_pk_bf16_f32 %0, %1, %2" : "=v"(D4) : "v"(pe[8]),  "v"(pe[9]));
        asm("v_cvt_pk_bf16_f32 %0, %1, %2" : "=v"(D5) : "v"(pe[10]), "v"(pe[11]));
        asm("v_cvt_pk_bf16_f32 %0, %1, %2" : "=v"(D6) : "v"(pe[12]), "v"(pe[13]));
        asm("v_cvt_pk_bf16_f32 %0, %1, %2" : "=v"(D7) : "v"(pe[14]), "v"(pe[15]));
        asm("v_permlane32_swap_b32 %0, %1" : "+v"(D0), "+v"(D2));
        asm("v_permlane32_swap_b32 %0, %1" : "+v"(D1), "+v"(D3));
        asm("v_permlane32_swap_b32 %0, %1" : "+v"(D4), "+v"(D6));
        asm("v_permlane32_swap_b32 %0, %1" : "+v"(D5), "+v"(D7));
        union { int i[4]; short8 s8; } u0, u1;
        u0.i[0] = D0; u0.i[1] = D1; u0.i[2] = D2; u0.i[3] = D3;
        u1.i[0] = D4; u1.i[1] = D5; u1.i[2] = D6; u1.i[3] = D7;
        pf[jt][0] = u0.s8;
        pf[jt][1] = u1.s8;
      }

#pragma unroll
      for (int dt = 0; dt < 4; ++dt) {
        const u16* vrow = vsp + (dt * 32 + l31) * 64;
        const int sw = (l31 & 7);
#pragma unroll
        for (int jt = 0; jt < 2; ++jt) {
          const short8 vf0 = *(const short8*)(vrow + (((jt * 4 + 0) + hi) ^ sw) * 8);
          const short8 vf1 = *(const short8*)(vrow + (((jt * 4 + 2) + hi) ^ sw) * 8);
          oacc[dt] = __builtin_amdgcn_mfma_f32_32x32x16_bf16(vf0, pf[jt][0], oacc[dt], 0, 0, 0);
          oacc[dt] = __builtin_amdgcn_mfma_f32_32x32x16_bf16(vf1, pf[jt][1], oacc[dt], 0, 0, 0);
        }
      }
    }

    __syncthreads();   // drains vmcnt (prefetch landed) + frees buf p
  }

  lrow += __shfl_xor(lrow, 32, 64);
  const float inv = 1.0f / lrow;

  u16* obase = o + ((size_t)(b * TSEQ + qi)) * CDIM + h * DHEAD;
#pragma unroll
  for (int dt = 0; dt < 4; ++dt)
#pragma unroll
    for (int a2 = 0; a2 < 4; ++a2) {
      u16x4 pkd;
#pragma unroll
      for (int r = 0; r < 4; ++r) pkd[r] = f2bf(oacc[dt][a2 * 4 + r] * inv);
      *(u16x4*)(obase + dt * 32 + a2 * 8 + hi * 4) = pkd;
    }
}

// ---------------------------------------------------------------------------
extern "C" void kernel_launch(void* const* d_in, const int* in_sizes, int n_in,
                              void* d_out, int out_size, void* d_ws, size_t ws_size,
                              hipStream_t stream) {
  (void)in_sizes; (void)n_in; (void)out_size; (void)ws_size;
  const float* x  = (const float*)d_in[0];
  const float* Wq = (const float*)d_in[1];
  const float* Wk = (const float*)d_in[2];
  const float* Wv = (const float*)d_in[3];
  const float* Wo = (const float*)d_in[4];
  float* out = (float*)d_out;

  char* ws = (char*)d_ws;
  const size_t WT = (size_t)CDIM * CDIM * sizeof(u16);   // 8 MiB
  const size_t QS = (size_t)MROWS * CDIM * sizeof(u16);  // 16 MiB
  u16* WqT = (u16*)(ws + 0 * WT);
  u16* WkT = (u16*)(ws + 1 * WT);
  u16* WvT = (u16*)(ws + 2 * WT);
  u16* WoT = (u16*)(ws + 3 * WT);
  u16* xb  = (u16*)(ws + 4 * WT);
  u16* qb  = (u16*)(ws + 4 * WT + 1 * QS);
  u16* kb  = (u16*)(ws + 4 * WT + 2 * QS);
  u16* vTb = (u16*)(ws + 4 * WT + 3 * QS);
  u16* ob  = (u16*)(ws + 4 * WT + 4 * QS);
  float* ct = (float*)(ws + 4 * WT + 5 * QS);
  float* st = ct + TSEQ * 64;

  transpose_kernel<<<dim3(64, 64, 5), dim3(32, 8), 0, stream>>>(
      Wq, Wk, Wv, Wo, WqT, WkT, WvT, WoT, x, xb);
  rope_table_kernel<<<dim3(TSEQ * 64 / 256), 256, 0, stream>>>(ct, st);
  gemm_bt_kernel<<<dim3(16, 3, 32), 256, 0, stream>>>(
      xb, WqT, WkT, WvT, qb, kb, vTb, 2, nullptr, ct, st);
  attn_kernel<<<dim3(16, 32), 256, 0, stream>>>(qb, kb, vTb, ob);
  gemm_bt_kernel<<<dim3(16, 1, 32), 256, 0, stream>>>(
      ob, WoT, WoT, WoT, nullptr, nullptr, nullptr, -1, out, nullptr, nullptr);
}